// Round 7
// baseline (187.286 us; speedup 1.0000x reference)
//
#include <hip/hip_runtime.h>
#include <stdint.h>

#define IN_F   8192
#define OUT_F  8192
#define BATCH  1024
#define BT     8              // batch rows staged in LDS per workgroup (16B/row)
#define NBT    (BATCH / BT)   // 128 batch tiles
#define MAIN_THREADS 1024     // 16 waves; 128KB LDS -> 1 WG/CU = 4 waves/SIMD
#define GROUPS_PER_WAVE 4     // 16 waves x 4 groups = 64 groups = half the columns
#define L_PREF 160            // ELL slots/column (max column count ~120; P(>160)~0)
#define XTILE_BYTES (IN_F * 16)   // 128 KB dynamic LDS

// --- two-phase ELL construction ---
#define NBUCKET 1024          // bucket = col >> 3 (8 columns/bucket)
#define P1_THREADS 1024
#define P1_PER 4              // 4 entries/thread -> 164 blocks
#define P1_CHUNK (P1_THREADS * P1_PER)   // 4096 entries per phase-1 block
#define P2_THREADS 1024
#define BIN_STRIDE (L_PREF + 1)          // 161 (odd -> LDS bank spread)
// build dynamic LDS: bins + ord + scnt + 3 stride-9 arrays
#define BUILD_LDS_BYTES ((64 * BIN_STRIDE * 2 + 64 * 8 + 64 * 9 * 3) * 4)

#if __has_builtin(__builtin_amdgcn_fdot2) && __has_builtin(__builtin_amdgcn_perm)
#define USE_DOT2 1
typedef _Float16 half2v __attribute__((ext_vector_type(2)));
#else
#define USE_DOT2 0
#endif

typedef float f32x2 __attribute__((ext_vector_type(2)));

// workspace dword layout: bcnt[1024] | counts[8192] | ELL slabs (bucket b at b*8L)

__device__ __forceinline__ unsigned f32_to_bf16_bits_rne(float f) {
    union { float f; unsigned u; } v; v.f = f;
    unsigned u = v.u;
    unsigned r = u + 0x7FFFu + ((u >> 16) & 1u);
    return r >> 16;
}
__device__ __forceinline__ float bf16_hi_bits_to_f32(unsigned b) {
    union { unsigned u; float f; } v; v.u = b & 0xFFFF0000u; return v.f;
}
__device__ __forceinline__ f32x2 unpack_pair(unsigned u) {
    union { unsigned u; float f; } lo, hi;
    lo.u = u << 16; hi.u = u & 0xFFFF0000u;
    f32x2 r; r.x = lo.f; r.y = hi.f; return r;
}

#if USE_DOT2
// weight value stored as f16 bits (more mantissa than bf16; vals ~N(0,1)/90 fit easily)
__device__ __forceinline__ unsigned val_bits(float f) {
    return (unsigned)__builtin_bit_cast(unsigned short, (_Float16)f);
}
__device__ __forceinline__ unsigned x_bits(float f) {
    return (unsigned)__builtin_bit_cast(unsigned short, (_Float16)f);
}
#else
__device__ __forceinline__ unsigned val_bits(float f) { return f32_to_bf16_bits_rne(f); }
__device__ __forceinline__ unsigned x_bits(float f)   { return f32_to_bf16_bits_rne(f); }
#endif

// ---------------- Phase 1: bin COO entries by col>>3 into bucket slabs ----------------
// Entry = (val16 << 16) | (row << 3) | (col & 7)  -- low 3 bits carry column-in-bucket;
// spmm masks them off (pk & 0xFFF8) so they are free payload.
__global__ __launch_bounds__(P1_THREADS) void bin_kernel(
        const int* __restrict__ rows, const int* __restrict__ cols,
        const float* __restrict__ vals,
        int* __restrict__ bcnt, unsigned* __restrict__ ell, int nnz, int L) {
    __shared__ int lcnt[NBUCKET];
    __shared__ int lbase[NBUCKET];
    __shared__ int gbase[NBUCKET];
    __shared__ int wsum[16];
    __shared__ unsigned stage[P1_CHUNK];          // 16KB
    __shared__ unsigned short smap[P1_CHUNK];     // 8KB: staged pos -> bucket

    int tid = threadIdx.x;
    int i0 = blockIdx.x * P1_CHUNK;
    lcnt[tid] = 0;                                // NBUCKET == P1_THREADS
    __syncthreads();

    unsigned mypk[P1_PER];
    int      myb[P1_PER];
    int      myrk[P1_PER];
#pragma unroll
    for (int k = 0; k < P1_PER; ++k) {
        int i = i0 + k * P1_THREADS + tid;
        myb[k] = -1;
        mypk[k] = 0;
        myrk[k] = 0;
        if (i < nnz) {
            int c = cols[i];
            mypk[k] = (val_bits(vals[i]) << 16) | ((unsigned)rows[i] << 3) | ((unsigned)c & 7u);
            myb[k] = c >> 3;
            myrk[k] = atomicAdd(&lcnt[c >> 3], 1);
        }
    }
    __syncthreads();

    // block-wide exclusive prefix of lcnt -> lbase
    {
        int wv = tid >> 6, ln = tid & 63;
        int v = lcnt[tid];
        int sc = v;
#pragma unroll
        for (int off = 1; off < 64; off <<= 1) {
            int o = __shfl_up(sc, off, 64);
            if (ln >= off) sc += o;
        }
        if (ln == 63) wsum[wv] = sc;
        __syncthreads();
        if (tid < 16) {
            int s = wsum[tid];
            int sl = s;
#pragma unroll
            for (int off = 1; off < 16; off <<= 1) {
                int o = __shfl_up(sl, off, 16);
                if (tid >= off) sl += o;
            }
            wsum[tid] = sl - s;                   // exclusive wave base
        }
        __syncthreads();
        lbase[tid] = sc - v + wsum[wv];
    }
    __syncthreads();

    // reserve global ranges: one device atomic per (block,bucket)
    {
        int lc = lcnt[tid];
        gbase[tid] = lc ? atomicAdd(&bcnt[tid], lc) : 0;
    }
    // stage entries into per-bucket runs in LDS
#pragma unroll
    for (int k = 0; k < P1_PER; ++k) {
        if (myb[k] >= 0) {
            int pos = lbase[myb[k]] + myrk[k];
            stage[pos] = mypk[k];
            smap[pos] = (unsigned short)myb[k];
        }
    }
    __syncthreads();

    // coalesced run copy-out
    int total = lbase[NBUCKET - 1] + lcnt[NBUCKET - 1];
    int cap = 8 * L;
    for (int i = tid; i < total; i += P1_THREADS) {
        int b = smap[i];
        int idx = gbase[b] + (i - lbase[b]);
        if (idx < cap)
            ell[(size_t)b * cap + idx] = stage[i];
    }
}

// ---------------- Phase 2: per-group, bin 8 buckets into 64 column lists ----------------
// Entries are class-major binned per column (class = row&7 = LDS bank-group), then a
// COORDINATED adaptive round-robin (one wave, lane=column, all pointers advancing in
// lockstep with stagger k0=c&7) interleaves classes across slots so that at any ELL
// slot the wave's 64 lanes spread ~8 per bank-group -> fewer ds_read_b128 conflicts.
// (Static per-column sort + rotation failed: phases drift, r4 A/B showed only -19%.)
// Slab rewritten in place in the quad-interleaved layout, zero-padded; counts written.
__global__ __launch_bounds__(P2_THREADS) void build_kernel(
        const int* __restrict__ bcnt, unsigned* __restrict__ ell,
        int* __restrict__ counts, int L) {
    extern __shared__ unsigned bshr[];
    unsigned* bins = bshr;                        // [64][BIN_STRIDE] class-major
    unsigned* ord  = bins + 64 * BIN_STRIDE;      // [64][BIN_STRIDE] slot-ordered
    int* scnt  = (int*)(ord + 64 * BIN_STRIDE);   // [64][8] counts -> cursors
    int* soff9 = scnt + 64 * 8;                   // [64][9] class-major offsets (padded)
    int* rem9  = soff9 + 64 * 9;                  // [64][9] remaining per class
    int* tak9  = rem9 + 64 * 9;                   // [64][9] taken per class
    __shared__ int qsh;

    int g = blockIdx.x;
    int tid = threadIdx.x;
    for (int i = tid; i < 64 * BIN_STRIDE; i += P2_THREADS) ord[i] = 0;
    if (tid < 512) scnt[tid] = 0;
    __syncthreads();

    unsigned* slab = ell + (size_t)g * (64 * L);
    int cap = 8 * L;

    // pass 1: count (col, row&7) sub-bins
#pragma unroll 1
    for (int q = 0; q < 8; ++q) {
        int cb = bcnt[g * 8 + q];
        if (cb > cap) cb = cap;
        const unsigned* bp = slab + q * cap;
        for (int i = tid; i < cb; i += P2_THREADS) {
            unsigned e = bp[i];
            int c64 = q * 8 + (int)(e & 7u);
            int sb = (int)((e >> 3) & 7u);        // row & 7 == LDS bank-group
            atomicAdd(&scnt[c64 * 8 + sb], 1);
        }
    }
    __syncthreads();

    // per-column class-major prefix -> soff9; clamped remains -> rem9; counts; reset scnt
    if (tid < 64) {
        int off = 0;
#pragma unroll
        for (int k = 0; k < 8; ++k) {
            int c = scnt[tid * 8 + k];
            soff9[tid * 9 + k] = off;
            int lim = L - off; if (lim < 0) lim = 0;
            rem9[tid * 9 + k] = c < lim ? c : lim;
            tak9[tid * 9 + k] = 0;
            off += c;
        }
        counts[g * 64 + tid] = off;
        int mc = min(off, L);
#pragma unroll
        for (int o = 32; o; o >>= 1) mc = max(mc, __shfl_xor(mc, o, 64));
        if (tid == 0) qsh = (mc + 3) >> 2;
#pragma unroll
        for (int k = 0; k < 8; ++k) scnt[tid * 8 + k] = 0;
    }
    __syncthreads();

    // pass 2: place entries class-major into bins (scnt as cursors)
#pragma unroll 1
    for (int q = 0; q < 8; ++q) {
        int cb = bcnt[g * 8 + q];
        if (cb > cap) cb = cap;
        const unsigned* bp = slab + q * cap;
        for (int i = tid; i < cb; i += P2_THREADS) {
            unsigned e = bp[i];
            int c64 = q * 8 + (int)(e & 7u);
            int sb = (int)((e >> 3) & 7u);
            int rk = atomicAdd(&scnt[c64 * 8 + sb], 1);
            int pos = soff9[c64 * 9 + sb] + rk;
            if (pos < L) bins[c64 * BIN_STRIDE + pos] = e;
        }
    }
    __syncthreads();

    // pass 3: coordinated adaptive round-robin interleave (one wave, lane = column).
    // Pointers advance in lockstep each slot; stagger k0=c&7 keeps ~8 lanes/class.
    if (tid < 64) {
        int c = tid;
        int cnt = counts[g * 64 + c];
        if (cnt > L) cnt = L;
        int k = c & 7;
        for (int s = 0; s < cnt; ++s) {
            while (rem9[c * 9 + k] == 0) k = (k + 1) & 7;   // sum(rem) = cnt-s > 0
            int t = tak9[c * 9 + k];
            unsigned e = bins[c * BIN_STRIDE + soff9[c * 9 + k] + t];
            tak9[c * 9 + k] = t + 1;
            rem9[c * 9 + k] -= 1;
            ord[c * BIN_STRIDE + s] = e;
            k = (k + 1) & 7;
        }
    }
    __syncthreads();   // also: all bucket reads done -> safe to overwrite slab

    int D = qsh << 8;                              // quads * 256 dwords
    for (int d = tid; d < D; d += P2_THREADS) {
        int q = d >> 8, r = d & 255;
        slab[d] = ord[(r >> 2) * BIN_STRIDE + q * 4 + (r & 3)];
    }
}

#if USE_DOT2
// LDS x-vector for one entry: 8 f16 batch values at row*16 bytes.
__device__ __forceinline__ uint4 ld_x16(const char* xbase, unsigned pk) {
    unsigned off = pk & 0xFFF8u;                 // row*8; LDS stride is 16 -> *2
    return *(const uint4*)(xbase + off * 2);
}
// One entry vs 8 staged batches via packed f16 FMA: 1 perm (val broadcast) +
// 4 v_pk_fma_f16 into f16x2 batch-pair accumulators. 10 arith / 2 entries;
// precision bounded by folding to f32 every 16 entries.
__device__ __forceinline__ void pk_entry(unsigned e, uint4 X,
        half2v& p0, half2v& p1, half2v& p2, half2v& p3) {
    half2v vv = __builtin_bit_cast(half2v, __builtin_amdgcn_perm(e, e, 0x03020302u));
    p0 = __builtin_elementwise_fma(__builtin_bit_cast(half2v, X.x), vv, p0);
    p1 = __builtin_elementwise_fma(__builtin_bit_cast(half2v, X.y), vv, p1);
    p2 = __builtin_elementwise_fma(__builtin_bit_cast(half2v, X.z), vv, p2);
    p3 = __builtin_elementwise_fma(__builtin_bit_cast(half2v, X.w), vv, p3);
}
#define PKQ(q, x0, x1, x2, x3) \
    do { pk_entry((q).x, (x0), p0, p1, p2, p3); pk_entry((q).y, (x1), p0, p1, p2, p3); \
         pk_entry((q).z, (x2), p0, p1, p2, p3); pk_entry((q).w, (x3), p0, p1, p2, p3); } while (0)
#define FOLD8() \
    do { a0 += (float)p0.x; a1 += (float)p0.y; a2 += (float)p1.x; a3 += (float)p1.y; \
         a4 += (float)p2.x; a5 += (float)p2.y; a6 += (float)p3.x; a7 += (float)p3.y; \
         p0 = half2v{}; p1 = half2v{}; p2 = half2v{}; p3 = half2v{}; } while (0)
#define LD4A(q) do { xA0 = ld_x16(xbase, (q).x); xA1 = ld_x16(xbase, (q).y); \
                     xA2 = ld_x16(xbase, (q).z); xA3 = ld_x16(xbase, (q).w); } while (0)
#define LD4B(q) do { xB0 = ld_x16(xbase, (q).x); xB1 = ld_x16(xbase, (q).y); \
                     xB2 = ld_x16(xbase, (q).z); xB3 = ld_x16(xbase, (q).w); } while (0)
#else
// Fallback: one ELL entry vs 8 staged batch rows (bf16 unpack + pk_fma)
__device__ __forceinline__ void process_entry8(unsigned pk, const char* xbase,
                                               f32x2& a01, f32x2& a23, f32x2& a45, f32x2& a67) {
    float val = bf16_hi_bits_to_f32(pk);
    f32x2 vv; vv.x = val; vv.y = val;
    unsigned off = pk & 0xFFF8u;
    uint4 d = *(const uint4*)(xbase + off * 2);
    a01 = __builtin_elementwise_fma(unpack_pair(d.x), vv, a01);
    a23 = __builtin_elementwise_fma(unpack_pair(d.y), vv, a23);
    a45 = __builtin_elementwise_fma(unpack_pair(d.z), vv, a45);
    a67 = __builtin_elementwise_fma(unpack_pair(d.w), vv, a67);
}
#endif

// Main SpMM: WG = (batch tile of 8) x (half the columns). 16 waves x 4 groups.
// 128KB dynamic LDS holds x[b0..b0+7, :] as uint4 (8 x 16-bit) per input row.
// Inner loop: 2-state software pipeline (globals prefetched 2 quads ahead, LDS
// refills separated from consumption by a full PKQ cluster); packed-f16
// accumulation folded into f32 every 2 iterations (16 entries).
__global__ __launch_bounds__(MAIN_THREADS) void spmm_kernel(
        const float* __restrict__ x,
        const float* __restrict__ bias,
        const int* __restrict__ counts,
        const unsigned* __restrict__ ell,
        float* __restrict__ out, int L) {
    extern __shared__ uint4 xl[];               // IN_F entries = 128 KB
    int w = blockIdx.x;
    int bt = w >> 1;
    int half = w & 1;
    int t = threadIdx.x;
    int b0 = bt * BT;
    int wave = t >> 6;
    int lane = t & 63;
    int n4cap = L >> 2;

    // Hoisted per-group trip counts + bias (global-only; overlaps with staging loads)
    int   n44[GROUPS_PER_WAVE];
    float bv4[GROUPS_PER_WAVE];
#pragma unroll
    for (int it = 0; it < GROUPS_PER_WAVE; ++it) {
        int g = half * 64 + wave * GROUPS_PER_WAVE + it;
        int col = (g << 6) + lane;
        int cnt = counts[col];
#pragma unroll
        for (int off = 32; off; off >>= 1) cnt = max(cnt, __shfl_xor(cnt, off, 64));
        int n4 = (cnt + 3) >> 2;
        n44[it] = min(n4, n4cap);
        bv4[it] = bias[col];
    }

    for (int r = t; r < IN_F; r += MAIN_THREADS) {
        unsigned u0 = x_bits(x[(b0 + 0) * IN_F + r]);
        unsigned u1 = x_bits(x[(b0 + 1) * IN_F + r]);
        unsigned u2 = x_bits(x[(b0 + 2) * IN_F + r]);
        unsigned u3 = x_bits(x[(b0 + 3) * IN_F + r]);
        unsigned u4 = x_bits(x[(b0 + 4) * IN_F + r]);
        unsigned u5 = x_bits(x[(b0 + 5) * IN_F + r]);
        unsigned u6 = x_bits(x[(b0 + 6) * IN_F + r]);
        unsigned u7 = x_bits(x[(b0 + 7) * IN_F + r]);
        uint4 d;
        d.x = (u1 << 16) | u0;
        d.y = (u3 << 16) | u2;
        d.z = (u5 << 16) | u4;
        d.w = (u7 << 16) | u6;
        xl[r] = d;
    }
    __syncthreads();

    const char* xbase = (const char*)xl;

#pragma unroll 1
    for (int it = 0; it < GROUPS_PER_WAVE; ++it) {
        int g = half * 64 + wave * GROUPS_PER_WAVE + it;
        int col = (g << 6) + lane;
        int n4 = n44[it];
        const uint4* ep = (const uint4*)(ell + (size_t)g * (L * 64));
        float bv = bv4[it];
#if USE_DOT2
        float a0 = 0.f, a1 = 0.f, a2 = 0.f, a3 = 0.f;
        float a4 = 0.f, a5 = 0.f, a6 = 0.f, a7 = 0.f;
        half2v p0 = half2v{}, p1 = half2v{}, p2 = half2v{}, p3 = half2v{};
        if (n4 > 0) {
            uint4 qA = ep[lane];
            uint4 xA0, xA1, xA2, xA3;
            LD4A(qA);
            uint4 qB;
            uint4 xB0, xB1, xB2, xB3;
            if (n4 > 1) {
                qB = ep[64 + lane];
                LD4B(qB);
            }
            int s4 = 2;
            int parity = 0;
#pragma unroll 1
            for (; s4 + 1 < n4; s4 += 2) {
                uint4 qC = ep[s4 * 64 + lane];          // global prefetch (quad s4)
                uint4 qD = ep[(s4 + 1) * 64 + lane];    // global prefetch (quad s4+1)
                PKQ(qA, xA0, xA1, xA2, xA3);            // consume quad s4-2
                qA = qC;
                LD4A(qA);                               // LDS refill for quad s4
                PKQ(qB, xB0, xB1, xB2, xB3);            // consume quad s4-1
                qB = qD;
                LD4B(qB);                               // LDS refill for quad s4+1
                if ((parity ^= 1) == 0) FOLD8();        // f32 fold every 16 entries
            }
            if (s4 < n4) {                              // one un-loaded quad remains
                uint4 qC = ep[s4 * 64 + lane];
                PKQ(qA, xA0, xA1, xA2, xA3);
                qA = qC;
                LD4A(qA);
                PKQ(qB, xB0, xB1, xB2, xB3);
                PKQ(qA, xA0, xA1, xA2, xA3);
            } else {
                PKQ(qA, xA0, xA1, xA2, xA3);
                if (n4 > 1) PKQ(qB, xB0, xB1, xB2, xB3);
            }
            FOLD8();
        }
        out[(size_t)(b0 + 0) * OUT_F + col] = a0 + bv;
        out[(size_t)(b0 + 1) * OUT_F + col] = a1 + bv;
        out[(size_t)(b0 + 2) * OUT_F + col] = a2 + bv;
        out[(size_t)(b0 + 3) * OUT_F + col] = a3 + bv;
        out[(size_t)(b0 + 4) * OUT_F + col] = a4 + bv;
        out[(size_t)(b0 + 5) * OUT_F + col] = a5 + bv;
        out[(size_t)(b0 + 6) * OUT_F + col] = a6 + bv;
        out[(size_t)(b0 + 7) * OUT_F + col] = a7 + bv;
#else
        f32x2 a01 = {0.f, 0.f}, a23 = {0.f, 0.f}, a45 = {0.f, 0.f}, a67 = {0.f, 0.f};
        if (n4 > 0) {
            uint4 q = ep[lane];
#pragma unroll 1
            for (int s4 = 1; s4 < n4; ++s4) {
                uint4 qn = ep[s4 * 64 + lane];
                process_entry8(q.x, xbase, a01, a23, a45, a67);
                process_entry8(q.y, xbase, a01, a23, a45, a67);
                process_entry8(q.z, xbase, a01, a23, a45, a67);
                process_entry8(q.w, xbase, a01, a23, a45, a67);
                q = qn;
            }
            process_entry8(q.x, xbase, a01, a23, a45, a67);
            process_entry8(q.y, xbase, a01, a23, a45, a67);
            process_entry8(q.z, xbase, a01, a23, a45, a67);
            process_entry8(q.w, xbase, a01, a23, a45, a67);
        }
        out[(size_t)(b0 + 0) * OUT_F + col] = a01.x + bv;
        out[(size_t)(b0 + 1) * OUT_F + col] = a01.y + bv;
        out[(size_t)(b0 + 2) * OUT_F + col] = a23.x + bv;
        out[(size_t)(b0 + 3) * OUT_F + col] = a23.y + bv;
        out[(size_t)(b0 + 4) * OUT_F + col] = a45.x + bv;
        out[(size_t)(b0 + 5) * OUT_F + col] = a45.y + bv;
        out[(size_t)(b0 + 6) * OUT_F + col] = a67.x + bv;
        out[(size_t)(b0 + 7) * OUT_F + col] = a67.y + bv;
#endif
    }
}

extern "C" void kernel_launch(void* const* d_in, const int* in_sizes, int n_in,
                              void* d_out, int out_size, void* d_ws, size_t ws_size,
                              hipStream_t stream) {
    const float* x      = (const float*)d_in[0];
    const float* values = (const float*)d_in[1];
    const float* bias   = (const float*)d_in[2];
    const int* rows = (const int*)d_in[3];
    const int* cols = (const int*)d_in[4];
    float* out = (float*)d_out;
    int nnz = in_sizes[1];

    int* bcnt   = (int*)d_ws;                    // 1024 dwords
    int* counts = bcnt + NBUCKET;                // 8192 dwords
    unsigned* ell = (unsigned*)(counts + 8192);  // 128 * 64 * L dwords

    // L = slots per column, multiple of 4, clamped to workspace capacity.
    long long cap_slots = ((long long)(ws_size / 4) - (NBUCKET + 8192)) / 8192;
    int L = (int)(cap_slots & ~3LL);
    if (L > L_PREF) L = L_PREF;
    if (L < 4) L = 4;

    static int attr_set = -1;                    // host-side only; no device effect
    if (attr_set < 0) {
        hipFuncSetAttribute((const void*)spmm_kernel,
                            hipFuncAttributeMaxDynamicSharedMemorySize, XTILE_BYTES);
        hipFuncSetAttribute((const void*)build_kernel,
                            hipFuncAttributeMaxDynamicSharedMemorySize, BUILD_LDS_BYTES);
        attr_set = 1;
    }

    hipMemsetAsync(bcnt, 0, NBUCKET * 4, stream);   // only bucket counters need zeroing
    int nb1 = (nnz + P1_CHUNK - 1) / P1_CHUNK;
    bin_kernel<<<nb1, P1_THREADS, 0, stream>>>(rows, cols, values, bcnt, ell, nnz, L);
    build_kernel<<<128, P2_THREADS, BUILD_LDS_BYTES, stream>>>(bcnt, ell, counts, L);
    spmm_kernel<<<NBT * 2, MAIN_THREADS, XTILE_BYTES, stream>>>(x, bias, counts, ell, out, L);
}

// Round 8
// 160.134 us; speedup vs baseline: 1.1696x; 1.1696x over previous
//
#include <hip/hip_runtime.h>
#include <stdint.h>

#define IN_F   8192
#define OUT_F  8192
#define BATCH  1024
#define BT     4              // batch rows staged in LDS per workgroup (8B/row)
#define NBT    (BATCH / BT)   // 256 batch tiles
#define MAIN_THREADS 1024     // 16 waves; 64KB LDS -> 2 WG/CU = 8 waves/SIMD
#define GROUPS_PER_WAVE 4     // 16 waves x 4 groups = 64 groups = half the columns
#define L_PREF 160            // ELL slots/column (max column count ~120; P(>160)~0)
#define XTILE_BYTES (IN_F * 8)    // 64 KB dynamic LDS

// --- two-phase ELL construction ---
#define NBUCKET 1024          // bucket = col >> 3 (8 columns/bucket)
#define P1_THREADS 1024
#define P1_PER 4              // 4 entries/thread -> 164 blocks
#define P1_CHUNK (P1_THREADS * P1_PER)   // 4096 entries per phase-1 block
#define P2_THREADS 1024
#define BIN_STRIDE (L_PREF + 1)          // 161 (odd -> LDS bank spread)

#if __has_builtin(__builtin_amdgcn_fdot2) && __has_builtin(__builtin_amdgcn_perm)
#define USE_DOT2 1
typedef _Float16 half2v __attribute__((ext_vector_type(2)));
#else
#define USE_DOT2 0
#endif

typedef float f32x2 __attribute__((ext_vector_type(2)));

// workspace dword layout: bcnt[1024] | counts[8192] | ELL slabs (bucket b at b*8L)

__device__ __forceinline__ unsigned f32_to_bf16_bits_rne(float f) {
    union { float f; unsigned u; } v; v.f = f;
    unsigned u = v.u;
    unsigned r = u + 0x7FFFu + ((u >> 16) & 1u);
    return r >> 16;
}
__device__ __forceinline__ float bf16_hi_bits_to_f32(unsigned b) {
    union { unsigned u; float f; } v; v.u = b & 0xFFFF0000u; return v.f;
}
__device__ __forceinline__ f32x2 unpack_pair(unsigned u) {
    union { unsigned u; float f; } lo, hi;
    lo.u = u << 16; hi.u = u & 0xFFFF0000u;
    f32x2 r; r.x = lo.f; r.y = hi.f; return r;
}

#if USE_DOT2
// weight value stored as f16 bits (more mantissa than bf16; vals ~N(0,1)/90 fit easily)
__device__ __forceinline__ unsigned val_bits(float f) {
    return (unsigned)__builtin_bit_cast(unsigned short, (_Float16)f);
}
__device__ __forceinline__ unsigned x_bits(float f) {
    return (unsigned)__builtin_bit_cast(unsigned short, (_Float16)f);
}
#else
__device__ __forceinline__ unsigned val_bits(float f) { return f32_to_bf16_bits_rne(f); }
__device__ __forceinline__ unsigned x_bits(float f)   { return f32_to_bf16_bits_rne(f); }
#endif

// ---------------- Phase 1: bin COO entries by col>>3 into bucket slabs ----------------
// Entry = (val16 << 16) | (row << 3) | (col & 7)  -- low 3 bits carry column-in-bucket;
// spmm masks them off (pk & 0xFFF8) so they are free payload.
__global__ __launch_bounds__(P1_THREADS) void bin_kernel(
        const int* __restrict__ rows, const int* __restrict__ cols,
        const float* __restrict__ vals,
        int* __restrict__ bcnt, unsigned* __restrict__ ell, int nnz, int L) {
    __shared__ int lcnt[NBUCKET];
    __shared__ int lbase[NBUCKET];
    __shared__ int gbase[NBUCKET];
    __shared__ int wsum[16];
    __shared__ unsigned stage[P1_CHUNK];          // 16KB
    __shared__ unsigned short smap[P1_CHUNK];     // 8KB: staged pos -> bucket

    int tid = threadIdx.x;
    int i0 = blockIdx.x * P1_CHUNK;
    lcnt[tid] = 0;                                // NBUCKET == P1_THREADS
    __syncthreads();

    unsigned mypk[P1_PER];
    int      myb[P1_PER];
    int      myrk[P1_PER];
#pragma unroll
    for (int k = 0; k < P1_PER; ++k) {
        int i = i0 + k * P1_THREADS + tid;
        myb[k] = -1;
        mypk[k] = 0;
        myrk[k] = 0;
        if (i < nnz) {
            int c = cols[i];
            mypk[k] = (val_bits(vals[i]) << 16) | ((unsigned)rows[i] << 3) | ((unsigned)c & 7u);
            myb[k] = c >> 3;
            myrk[k] = atomicAdd(&lcnt[c >> 3], 1);
        }
    }
    __syncthreads();

    // block-wide exclusive prefix of lcnt -> lbase
    {
        int wv = tid >> 6, ln = tid & 63;
        int v = lcnt[tid];
        int sc = v;
#pragma unroll
        for (int off = 1; off < 64; off <<= 1) {
            int o = __shfl_up(sc, off, 64);
            if (ln >= off) sc += o;
        }
        if (ln == 63) wsum[wv] = sc;
        __syncthreads();
        if (tid < 16) {
            int s = wsum[tid];
            int sl = s;
#pragma unroll
            for (int off = 1; off < 16; off <<= 1) {
                int o = __shfl_up(sl, off, 16);
                if (tid >= off) sl += o;
            }
            wsum[tid] = sl - s;                   // exclusive wave base
        }
        __syncthreads();
        lbase[tid] = sc - v + wsum[wv];
    }
    __syncthreads();

    // reserve global ranges: one device atomic per (block,bucket)
    {
        int lc = lcnt[tid];
        gbase[tid] = lc ? atomicAdd(&bcnt[tid], lc) : 0;
    }
    // stage entries into per-bucket runs in LDS
#pragma unroll
    for (int k = 0; k < P1_PER; ++k) {
        if (myb[k] >= 0) {
            int pos = lbase[myb[k]] + myrk[k];
            stage[pos] = mypk[k];
            smap[pos] = (unsigned short)myb[k];
        }
    }
    __syncthreads();

    // coalesced run copy-out
    int total = lbase[NBUCKET - 1] + lcnt[NBUCKET - 1];
    int cap = 8 * L;
    for (int i = tid; i < total; i += P1_THREADS) {
        int b = smap[i];
        int idx = gbase[b] + (i - lbase[b]);
        if (idx < cap)
            ell[(size_t)b * cap + idx] = stage[i];
    }
}

// ---------------- Phase 2: per-group, bin 8 buckets into 64 column lists ----------------
// Per-column entries are counting-sorted by bank-group (row&7) and concatenated
// with rotation start = (c64&7), then the slab is rewritten in place in the
// quad-interleaved layout, zero-padded; counts written. (Reverted to r6 version:
// the coordinated round-robin interleave (r7) cut conflicts only 8% and cost
// +35us in a serial 1-wave pass -- conflict floor is structural for wide LDS reads.)
__global__ __launch_bounds__(P2_THREADS) void build_kernel(
        const int* __restrict__ bcnt, unsigned* __restrict__ ell,
        int* __restrict__ counts, int L) {
    __shared__ unsigned bins[64 * BIN_STRIDE];    // 41.2KB
    __shared__ int scnt[64 * 8];                  // per (col, row&7) sub-counts
    __shared__ int soff[64 * 8];                  // rotated sub-bin offsets
    __shared__ int qsh;
    int g = blockIdx.x;
    int tid = threadIdx.x;
    for (int i = tid; i < 64 * BIN_STRIDE; i += P2_THREADS) bins[i] = 0;
    if (tid < 512) scnt[tid] = 0;
    __syncthreads();

    unsigned* slab = ell + (size_t)g * (64 * L);
    int cap = 8 * L;

    // pass 1: count (col, row&7) sub-bins
#pragma unroll 1
    for (int q = 0; q < 8; ++q) {
        int cb = bcnt[g * 8 + q];
        if (cb > cap) cb = cap;
        const unsigned* bp = slab + q * cap;
        for (int i = tid; i < cb; i += P2_THREADS) {
            unsigned e = bp[i];
            int c64 = q * 8 + (int)(e & 7u);
            int sb = (int)((e >> 3) & 7u);        // row & 7 == LDS bank-group
            atomicAdd(&scnt[c64 * 8 + sb], 1);
        }
    }
    __syncthreads();

    // per-column rotated prefix -> soff; column totals -> counts; reset scnt for ranks
    if (tid < 64) {
        int rot = tid & 7;
        int off = 0;
#pragma unroll
        for (int k = 0; k < 8; ++k) {
            int sb = (k + rot) & 7;
            soff[tid * 8 + sb] = off;
            off += scnt[tid * 8 + sb];
        }
        counts[g * 64 + tid] = off;
        int mc = min(off, L);
#pragma unroll
        for (int o = 32; o; o >>= 1) mc = max(mc, __shfl_xor(mc, o, 64));
        if (tid == 0) qsh = (mc + 3) >> 2;
#pragma unroll
        for (int k = 0; k < 8; ++k) scnt[tid * 8 + k] = 0;
    }
    __syncthreads();

    // pass 2: place entries at rotated sub-bin positions
#pragma unroll 1
    for (int q = 0; q < 8; ++q) {
        int cb = bcnt[g * 8 + q];
        if (cb > cap) cb = cap;
        const unsigned* bp = slab + q * cap;
        for (int i = tid; i < cb; i += P2_THREADS) {
            unsigned e = bp[i];
            int c64 = q * 8 + (int)(e & 7u);
            int sb = (int)((e >> 3) & 7u);
            int rk = atomicAdd(&scnt[c64 * 8 + sb], 1);
            int pos = soff[c64 * 8 + sb] + rk;
            if (pos < L) bins[c64 * BIN_STRIDE + pos] = e;
        }
    }
    __syncthreads();   // all bucket reads done -> safe to overwrite slab

    int D = qsh << 8;                              // quads * 256 dwords
    for (int d = tid; d < D; d += P2_THREADS) {
        int q = d >> 8, r = d & 255;
        slab[d] = bins[(r >> 2) * BIN_STRIDE + q * 4 + (r & 3)];
    }
}

#if USE_DOT2
// LDS x-vector for one entry: 4 f16 batch values at row*8 bytes.
__device__ __forceinline__ uint2 ld_x8(const char* xbase, unsigned pk) {
    unsigned off = pk & 0xFFF8u;                 // row*8 == byte offset (8B/row)
    return *(const uint2*)(xbase + off);
}
// One entry vs 4 staged batches via packed f16 FMA: 1 perm (val broadcast) +
// 2 v_pk_fma_f16 into f16x2 batch-pair accumulators; fold to f32 every 16 entries.
__device__ __forceinline__ void pk_entry(unsigned e, uint2 X, half2v& p0, half2v& p1) {
    half2v vv = __builtin_bit_cast(half2v, __builtin_amdgcn_perm(e, e, 0x03020302u));
    p0 = __builtin_elementwise_fma(__builtin_bit_cast(half2v, X.x), vv, p0);
    p1 = __builtin_elementwise_fma(__builtin_bit_cast(half2v, X.y), vv, p1);
}
#define PKQ(q, x0, x1, x2, x3) \
    do { pk_entry((q).x, (x0), p0, p1); pk_entry((q).y, (x1), p0, p1); \
         pk_entry((q).z, (x2), p0, p1); pk_entry((q).w, (x3), p0, p1); } while (0)
#define FOLD4() \
    do { a0 += (float)p0.x; a1 += (float)p0.y; a2 += (float)p1.x; a3 += (float)p1.y; \
         p0 = half2v{}; p1 = half2v{}; } while (0)
#define LD4A(q) do { xA0 = ld_x8(xbase, (q).x); xA1 = ld_x8(xbase, (q).y); \
                     xA2 = ld_x8(xbase, (q).z); xA3 = ld_x8(xbase, (q).w); } while (0)
#define LD4B(q) do { xB0 = ld_x8(xbase, (q).x); xB1 = ld_x8(xbase, (q).y); \
                     xB2 = ld_x8(xbase, (q).z); xB3 = ld_x8(xbase, (q).w); } while (0)
#else
// Fallback: one ELL entry vs 4 staged batch rows (bf16 unpack + pk_fma)
__device__ __forceinline__ void process_entry4(unsigned pk, const char* xbase,
                                               f32x2& a01, f32x2& a23) {
    float val = bf16_hi_bits_to_f32(pk);
    f32x2 vv; vv.x = val; vv.y = val;
    unsigned off = pk & 0xFFF8u;
    uint2 d = *(const uint2*)(xbase + off);
    a01 = __builtin_elementwise_fma(unpack_pair(d.x), vv, a01);
    a23 = __builtin_elementwise_fma(unpack_pair(d.y), vv, a23);
}
#endif

// Main SpMM: WG = (batch tile of 4) x (half the columns). 16 waves x 4 groups.
// 64KB dynamic LDS holds x[b0..b0+3, :] as uint2 (4 x f16) per input row ->
// 2 blocks/CU = 8 waves/SIMD (was 4): doubles latency-hiding for the LDS-read
// dependency stalls that dominate the wall (LDS pipe ~67% busy, rest exposed).
// Inner loop: 2-state software pipeline (globals prefetched 2 quads ahead, LDS
// refills separated from consumption by a full PKQ cluster); packed-f16
// accumulation folded into f32 every 2 iterations (16 entries).
__global__ __launch_bounds__(MAIN_THREADS, 8) void spmm_kernel(
        const float* __restrict__ x,
        const float* __restrict__ bias,
        const int* __restrict__ counts,
        const unsigned* __restrict__ ell,
        float* __restrict__ out, int L) {
    extern __shared__ uint2 xl[];               // IN_F entries = 64 KB
    int w = blockIdx.x;
    int bt = w >> 1;
    int half = w & 1;
    int t = threadIdx.x;
    int b0 = bt * BT;
    int wave = t >> 6;
    int lane = t & 63;
    int n4cap = L >> 2;

    // Hoisted per-group trip counts + bias (global-only; overlaps with staging loads)
    int   n44[GROUPS_PER_WAVE];
    float bv4[GROUPS_PER_WAVE];
#pragma unroll
    for (int it = 0; it < GROUPS_PER_WAVE; ++it) {
        int g = half * 64 + wave * GROUPS_PER_WAVE + it;
        int col = (g << 6) + lane;
        int cnt = counts[col];
#pragma unroll
        for (int off = 32; off; off >>= 1) cnt = max(cnt, __shfl_xor(cnt, off, 64));
        int n4 = (cnt + 3) >> 2;
        n44[it] = min(n4, n4cap);
        bv4[it] = bias[col];
    }

    for (int r = t; r < IN_F; r += MAIN_THREADS) {
        unsigned u0 = x_bits(x[(b0 + 0) * IN_F + r]);
        unsigned u1 = x_bits(x[(b0 + 1) * IN_F + r]);
        unsigned u2 = x_bits(x[(b0 + 2) * IN_F + r]);
        unsigned u3 = x_bits(x[(b0 + 3) * IN_F + r]);
        uint2 d;
        d.x = (u1 << 16) | u0;
        d.y = (u3 << 16) | u2;
        xl[r] = d;
    }
    __syncthreads();

    const char* xbase = (const char*)xl;

#pragma unroll 1
    for (int it = 0; it < GROUPS_PER_WAVE; ++it) {
        int g = half * 64 + wave * GROUPS_PER_WAVE + it;
        int col = (g << 6) + lane;
        int n4 = n44[it];
        const uint4* ep = (const uint4*)(ell + (size_t)g * (L * 64));
        float bv = bv4[it];
#if USE_DOT2
        float a0 = 0.f, a1 = 0.f, a2 = 0.f, a3 = 0.f;
        half2v p0 = half2v{}, p1 = half2v{};
        if (n4 > 0) {
            uint4 qA = ep[lane];
            uint2 xA0, xA1, xA2, xA3;
            LD4A(qA);
            uint4 qB;
            uint2 xB0, xB1, xB2, xB3;
            if (n4 > 1) {
                qB = ep[64 + lane];
                LD4B(qB);
            }
            int s4 = 2;
            int parity = 0;
#pragma unroll 1
            for (; s4 + 1 < n4; s4 += 2) {
                uint4 qC = ep[s4 * 64 + lane];          // global prefetch (quad s4)
                uint4 qD = ep[(s4 + 1) * 64 + lane];    // global prefetch (quad s4+1)
                PKQ(qA, xA0, xA1, xA2, xA3);            // consume quad s4-2
                qA = qC;
                LD4A(qA);                               // LDS refill for quad s4
                PKQ(qB, xB0, xB1, xB2, xB3);            // consume quad s4-1
                qB = qD;
                LD4B(qB);                               // LDS refill for quad s4+1
                if ((parity ^= 1) == 0) FOLD4();        // f32 fold every 16 entries
            }
            if (s4 < n4) {                              // one un-loaded quad remains
                uint4 qC = ep[s4 * 64 + lane];
                PKQ(qA, xA0, xA1, xA2, xA3);
                qA = qC;
                LD4A(qA);
                PKQ(qB, xB0, xB1, xB2, xB3);
                PKQ(qA, xA0, xA1, xA2, xA3);
            } else {
                PKQ(qA, xA0, xA1, xA2, xA3);
                if (n4 > 1) PKQ(qB, xB0, xB1, xB2, xB3);
            }
            FOLD4();
        }
        out[(size_t)(b0 + 0) * OUT_F + col] = a0 + bv;
        out[(size_t)(b0 + 1) * OUT_F + col] = a1 + bv;
        out[(size_t)(b0 + 2) * OUT_F + col] = a2 + bv;
        out[(size_t)(b0 + 3) * OUT_F + col] = a3 + bv;
#else
        f32x2 a01 = {0.f, 0.f}, a23 = {0.f, 0.f};
        if (n4 > 0) {
            uint4 q = ep[lane];
#pragma unroll 1
            for (int s4 = 1; s4 < n4; ++s4) {
                uint4 qn = ep[s4 * 64 + lane];
                process_entry4(q.x, xbase, a01, a23);
                process_entry4(q.y, xbase, a01, a23);
                process_entry4(q.z, xbase, a01, a23);
                process_entry4(q.w, xbase, a01, a23);
                q = qn;
            }
            process_entry4(q.x, xbase, a01, a23);
            process_entry4(q.y, xbase, a01, a23);
            process_entry4(q.z, xbase, a01, a23);
            process_entry4(q.w, xbase, a01, a23);
        }
        out[(size_t)(b0 + 0) * OUT_F + col] = a01.x + bv;
        out[(size_t)(b0 + 1) * OUT_F + col] = a01.y + bv;
        out[(size_t)(b0 + 2) * OUT_F + col] = a23.x + bv;
        out[(size_t)(b0 + 3) * OUT_F + col] = a23.y + bv;
#endif
    }
}

extern "C" void kernel_launch(void* const* d_in, const int* in_sizes, int n_in,
                              void* d_out, int out_size, void* d_ws, size_t ws_size,
                              hipStream_t stream) {
    const float* x      = (const float*)d_in[0];
    const float* values = (const float*)d_in[1];
    const float* bias   = (const float*)d_in[2];
    const int* rows = (const int*)d_in[3];
    const int* cols = (const int*)d_in[4];
    float* out = (float*)d_out;
    int nnz = in_sizes[1];

    int* bcnt   = (int*)d_ws;                    // 1024 dwords
    int* counts = bcnt + NBUCKET;                // 8192 dwords
    unsigned* ell = (unsigned*)(counts + 8192);  // 128 * 64 * L dwords

    // L = slots per column, multiple of 4, clamped to workspace capacity.
    long long cap_slots = ((long long)(ws_size / 4) - (NBUCKET + 8192)) / 8192;
    int L = (int)(cap_slots & ~3LL);
    if (L > L_PREF) L = L_PREF;
    if (L < 4) L = 4;

    static int attr_set = -1;                    // host-side only; no device effect
    if (attr_set < 0) {
        hipFuncSetAttribute((const void*)spmm_kernel,
                            hipFuncAttributeMaxDynamicSharedMemorySize, XTILE_BYTES);
        attr_set = 1;
    }

    hipMemsetAsync(bcnt, 0, NBUCKET * 4, stream);   // only bucket counters need zeroing
    int nb1 = (nnz + P1_CHUNK - 1) / P1_CHUNK;
    bin_kernel<<<nb1, P1_THREADS, 0, stream>>>(rows, cols, values, bcnt, ell, nnz, L);
    build_kernel<<<128, P2_THREADS, 0, stream>>>(bcnt, ell, counts, L);
    spmm_kernel<<<NBT * 2, MAIN_THREADS, XTILE_BYTES, stream>>>(x, bias, counts, ell, out, L);
}

// Round 9
// 152.016 us; speedup vs baseline: 1.2320x; 1.0534x over previous
//
#include <hip/hip_runtime.h>
#include <stdint.h>

#define IN_F   8192
#define OUT_F  8192
#define BATCH  1024
#define BT     8              // batch rows staged in LDS per workgroup (16B/row)
#define NBT    (BATCH / BT)   // 128 batch tiles
#define MAIN_THREADS 1024     // 16 waves; 128KB LDS -> 1 WG/CU = 4 waves/SIMD
#define GROUPS_PER_WAVE 4     // 16 waves x 4 groups = 64 groups = half the columns
#define L_PREF 160            // ELL slots/column (max column count ~120; P(>160)~0)
#define XTILE_BYTES (IN_F * 16)   // 128 KB dynamic LDS

// --- two-phase ELL construction ---
#define NBUCKET 1024          // bucket = col >> 3 (8 columns/bucket)
#define P1_THREADS 1024
#define P1_PER 4              // 4 entries/thread -> 164 blocks
#define P1_CHUNK (P1_THREADS * P1_PER)   // 4096 entries per phase-1 block
#define P2_THREADS 1024
#define BIN_STRIDE (L_PREF + 1)          // 161 (odd -> LDS bank spread)

#if __has_builtin(__builtin_amdgcn_fdot2) && __has_builtin(__builtin_amdgcn_perm)
#define USE_DOT2 1
typedef _Float16 half2v __attribute__((ext_vector_type(2)));
#else
#define USE_DOT2 0
#endif

typedef float f32x2 __attribute__((ext_vector_type(2)));

// workspace dword layout: bcnt[1024] | counts[8192] | ELL slabs (bucket b at b*8L)

__device__ __forceinline__ unsigned f32_to_bf16_bits_rne(float f) {
    union { float f; unsigned u; } v; v.f = f;
    unsigned u = v.u;
    unsigned r = u + 0x7FFFu + ((u >> 16) & 1u);
    return r >> 16;
}
__device__ __forceinline__ float bf16_hi_bits_to_f32(unsigned b) {
    union { unsigned u; float f; } v; v.u = b & 0xFFFF0000u; return v.f;
}
__device__ __forceinline__ f32x2 unpack_pair(unsigned u) {
    union { unsigned u; float f; } lo, hi;
    lo.u = u << 16; hi.u = u & 0xFFFF0000u;
    f32x2 r; r.x = lo.f; r.y = hi.f; return r;
}

#if USE_DOT2
// weight value stored as f16 bits (more mantissa than bf16; vals ~N(0,1)/90 fit easily)
__device__ __forceinline__ unsigned val_bits(float f) {
    return (unsigned)__builtin_bit_cast(unsigned short, (_Float16)f);
}
__device__ __forceinline__ unsigned x_bits(float f) {
    return (unsigned)__builtin_bit_cast(unsigned short, (_Float16)f);
}
#else
__device__ __forceinline__ unsigned val_bits(float f) { return f32_to_bf16_bits_rne(f); }
__device__ __forceinline__ unsigned x_bits(float f)   { return f32_to_bf16_bits_rne(f); }
#endif

// ---------------- Phase 1: bin COO entries by col>>3 into bucket slabs ----------------
// Entry = (val16 << 16) | (row << 3) | (col & 7)  -- low 3 bits carry column-in-bucket;
// spmm masks them off (pk & 0xFFF8) so they are free payload.
__global__ __launch_bounds__(P1_THREADS) void bin_kernel(
        const int* __restrict__ rows, const int* __restrict__ cols,
        const float* __restrict__ vals,
        int* __restrict__ bcnt, unsigned* __restrict__ ell, int nnz, int L) {
    __shared__ int lcnt[NBUCKET];
    __shared__ int lbase[NBUCKET];
    __shared__ int gbase[NBUCKET];
    __shared__ int wsum[16];
    __shared__ unsigned stage[P1_CHUNK];          // 16KB
    __shared__ unsigned short smap[P1_CHUNK];     // 8KB: staged pos -> bucket

    int tid = threadIdx.x;
    int i0 = blockIdx.x * P1_CHUNK;
    lcnt[tid] = 0;                                // NBUCKET == P1_THREADS
    __syncthreads();

    unsigned mypk[P1_PER];
    int      myb[P1_PER];
    int      myrk[P1_PER];
#pragma unroll
    for (int k = 0; k < P1_PER; ++k) {
        int i = i0 + k * P1_THREADS + tid;
        myb[k] = -1;
        mypk[k] = 0;
        myrk[k] = 0;
        if (i < nnz) {
            int c = cols[i];
            mypk[k] = (val_bits(vals[i]) << 16) | ((unsigned)rows[i] << 3) | ((unsigned)c & 7u);
            myb[k] = c >> 3;
            myrk[k] = atomicAdd(&lcnt[c >> 3], 1);
        }
    }
    __syncthreads();

    // block-wide exclusive prefix of lcnt -> lbase
    {
        int wv = tid >> 6, ln = tid & 63;
        int v = lcnt[tid];
        int sc = v;
#pragma unroll
        for (int off = 1; off < 64; off <<= 1) {
            int o = __shfl_up(sc, off, 64);
            if (ln >= off) sc += o;
        }
        if (ln == 63) wsum[wv] = sc;
        __syncthreads();
        if (tid < 16) {
            int s = wsum[tid];
            int sl = s;
#pragma unroll
            for (int off = 1; off < 16; off <<= 1) {
                int o = __shfl_up(sl, off, 16);
                if (tid >= off) sl += o;
            }
            wsum[tid] = sl - s;                   // exclusive wave base
        }
        __syncthreads();
        lbase[tid] = sc - v + wsum[wv];
    }
    __syncthreads();

    // reserve global ranges: one device atomic per (block,bucket)
    {
        int lc = lcnt[tid];
        gbase[tid] = lc ? atomicAdd(&bcnt[tid], lc) : 0;
    }
    // stage entries into per-bucket runs in LDS
#pragma unroll
    for (int k = 0; k < P1_PER; ++k) {
        if (myb[k] >= 0) {
            int pos = lbase[myb[k]] + myrk[k];
            stage[pos] = mypk[k];
            smap[pos] = (unsigned short)myb[k];
        }
    }
    __syncthreads();

    // coalesced run copy-out
    int total = lbase[NBUCKET - 1] + lcnt[NBUCKET - 1];
    int cap = 8 * L;
    for (int i = tid; i < total; i += P1_THREADS) {
        int b = smap[i];
        int idx = gbase[b] + (i - lbase[b]);
        if (idx < cap)
            ell[(size_t)b * cap + idx] = stage[i];
    }
}

// ---------------- Phase 2: per-group, bin 8 buckets into 64 column lists ----------------
// Per-column entries are counting-sorted by bank-group (row&7) and concatenated
// with rotation start = (c64&7), then the slab is rewritten in place in the
// quad-interleaved layout, zero-padded; counts written. (r7's coordinated
// round-robin interleave cut conflicts only 8% for +35us serial cost; r8's BT=4
// TLP doubled occupancy but regressed -- LDS pipe is saturated, not latency-bound.)
__global__ __launch_bounds__(P2_THREADS) void build_kernel(
        const int* __restrict__ bcnt, unsigned* __restrict__ ell,
        int* __restrict__ counts, int L) {
    __shared__ unsigned bins[64 * BIN_STRIDE];    // 41.2KB
    __shared__ int scnt[64 * 8];                  // per (col, row&7) sub-counts
    __shared__ int soff[64 * 8];                  // rotated sub-bin offsets
    __shared__ int qsh;
    int g = blockIdx.x;
    int tid = threadIdx.x;
    for (int i = tid; i < 64 * BIN_STRIDE; i += P2_THREADS) bins[i] = 0;
    if (tid < 512) scnt[tid] = 0;
    __syncthreads();

    unsigned* slab = ell + (size_t)g * (64 * L);
    int cap = 8 * L;

    // pass 1: count (col, row&7) sub-bins
#pragma unroll 1
    for (int q = 0; q < 8; ++q) {
        int cb = bcnt[g * 8 + q];
        if (cb > cap) cb = cap;
        const unsigned* bp = slab + q * cap;
        for (int i = tid; i < cb; i += P2_THREADS) {
            unsigned e = bp[i];
            int c64 = q * 8 + (int)(e & 7u);
            int sb = (int)((e >> 3) & 7u);        // row & 7 == LDS bank-group
            atomicAdd(&scnt[c64 * 8 + sb], 1);
        }
    }
    __syncthreads();

    // per-column rotated prefix -> soff; column totals -> counts; reset scnt for ranks
    if (tid < 64) {
        int rot = tid & 7;
        int off = 0;
#pragma unroll
        for (int k = 0; k < 8; ++k) {
            int sb = (k + rot) & 7;
            soff[tid * 8 + sb] = off;
            off += scnt[tid * 8 + sb];
        }
        counts[g * 64 + tid] = off;
        int mc = min(off, L);
#pragma unroll
        for (int o = 32; o; o >>= 1) mc = max(mc, __shfl_xor(mc, o, 64));
        if (tid == 0) qsh = (mc + 3) >> 2;
#pragma unroll
        for (int k = 0; k < 8; ++k) scnt[tid * 8 + k] = 0;
    }
    __syncthreads();

    // pass 2: place entries at rotated sub-bin positions
#pragma unroll 1
    for (int q = 0; q < 8; ++q) {
        int cb = bcnt[g * 8 + q];
        if (cb > cap) cb = cap;
        const unsigned* bp = slab + q * cap;
        for (int i = tid; i < cb; i += P2_THREADS) {
            unsigned e = bp[i];
            int c64 = q * 8 + (int)(e & 7u);
            int sb = (int)((e >> 3) & 7u);
            int rk = atomicAdd(&scnt[c64 * 8 + sb], 1);
            int pos = soff[c64 * 8 + sb] + rk;
            if (pos < L) bins[c64 * BIN_STRIDE + pos] = e;
        }
    }
    __syncthreads();   // all bucket reads done -> safe to overwrite slab

    int D = qsh << 8;                              // quads * 256 dwords
    for (int d = tid; d < D; d += P2_THREADS) {
        int q = d >> 8, r = d & 255;
        slab[d] = bins[(r >> 2) * BIN_STRIDE + q * 4 + (r & 3)];
    }
}

#if USE_DOT2
// LDS x-vector for one entry: 8 f16 batch values at row*16 bytes.
__device__ __forceinline__ uint4 ld_x16(const char* xbase, unsigned pk) {
    unsigned off = pk & 0xFFF8u;                 // row*8; LDS stride is 16 -> *2
    return *(const uint4*)(xbase + off * 2);
}
// One entry vs 8 staged batches via packed f16 FMA: 1 perm (val broadcast) +
// 4 v_pk_fma_f16 into f16x2 batch-pair accumulators. 10 arith / 2 entries;
// precision bounded by folding to f32 every 16 entries.
__device__ __forceinline__ void pk_entry(unsigned e, uint4 X,
        half2v& p0, half2v& p1, half2v& p2, half2v& p3) {
    half2v vv = __builtin_bit_cast(half2v, __builtin_amdgcn_perm(e, e, 0x03020302u));
    p0 = __builtin_elementwise_fma(__builtin_bit_cast(half2v, X.x), vv, p0);
    p1 = __builtin_elementwise_fma(__builtin_bit_cast(half2v, X.y), vv, p1);
    p2 = __builtin_elementwise_fma(__builtin_bit_cast(half2v, X.z), vv, p2);
    p3 = __builtin_elementwise_fma(__builtin_bit_cast(half2v, X.w), vv, p3);
}
#define PKQ(q, x0, x1, x2, x3) \
    do { pk_entry((q).x, (x0), p0, p1, p2, p3); pk_entry((q).y, (x1), p0, p1, p2, p3); \
         pk_entry((q).z, (x2), p0, p1, p2, p3); pk_entry((q).w, (x3), p0, p1, p2, p3); } while (0)
#define FOLD8() \
    do { a0 += (float)p0.x; a1 += (float)p0.y; a2 += (float)p1.x; a3 += (float)p1.y; \
         a4 += (float)p2.x; a5 += (float)p2.y; a6 += (float)p3.x; a7 += (float)p3.y; \
         p0 = half2v{}; p1 = half2v{}; p2 = half2v{}; p3 = half2v{}; } while (0)
#define LD4A(q) do { xA0 = ld_x16(xbase, (q).x); xA1 = ld_x16(xbase, (q).y); \
                     xA2 = ld_x16(xbase, (q).z); xA3 = ld_x16(xbase, (q).w); } while (0)
#define LD4B(q) do { xB0 = ld_x16(xbase, (q).x); xB1 = ld_x16(xbase, (q).y); \
                     xB2 = ld_x16(xbase, (q).z); xB3 = ld_x16(xbase, (q).w); } while (0)
#else
// Fallback: one ELL entry vs 8 staged batch rows (bf16 unpack + pk_fma)
__device__ __forceinline__ void process_entry8(unsigned pk, const char* xbase,
                                               f32x2& a01, f32x2& a23, f32x2& a45, f32x2& a67) {
    float val = bf16_hi_bits_to_f32(pk);
    f32x2 vv; vv.x = val; vv.y = val;
    unsigned off = pk & 0xFFF8u;
    uint4 d = *(const uint4*)(xbase + off * 2);
    a01 = __builtin_elementwise_fma(unpack_pair(d.x), vv, a01);
    a23 = __builtin_elementwise_fma(unpack_pair(d.y), vv, a23);
    a45 = __builtin_elementwise_fma(unpack_pair(d.z), vv, a45);
    a67 = __builtin_elementwise_fma(unpack_pair(d.w), vv, a67);
}
#endif

// Main SpMM: WG = (batch tile of 8) x (half the columns). 16 waves x 4 groups.
// 128KB dynamic LDS holds x[b0..b0+7, :] as uint4 (8 x 16-bit) per input row.
// Inner loop: 2-state software pipeline (globals prefetched 2 quads ahead, LDS
// refills separated from consumption by a full PKQ cluster); packed-f16
// accumulation folded into f32 every 2 iterations (16 entries).
// BT=8 / 1 block/CU is the measured optimum: BT=4 @ 2 blocks/CU regressed (r8,
// doubled per-entry overhead), conflict shaping saturates at -8..-19% (r4/r7).
__global__ __launch_bounds__(MAIN_THREADS) void spmm_kernel(
        const float* __restrict__ x,
        const float* __restrict__ bias,
        const int* __restrict__ counts,
        const unsigned* __restrict__ ell,
        float* __restrict__ out, int L) {
    extern __shared__ uint4 xl[];               // IN_F entries = 128 KB
    int w = blockIdx.x;
    int bt = w >> 1;
    int half = w & 1;
    int t = threadIdx.x;
    int b0 = bt * BT;
    int wave = t >> 6;
    int lane = t & 63;
    int n4cap = L >> 2;

    // Hoisted per-group trip counts + bias (global-only; overlaps with staging loads)
    int   n44[GROUPS_PER_WAVE];
    float bv4[GROUPS_PER_WAVE];
#pragma unroll
    for (int it = 0; it < GROUPS_PER_WAVE; ++it) {
        int g = half * 64 + wave * GROUPS_PER_WAVE + it;
        int col = (g << 6) + lane;
        int cnt = counts[col];
#pragma unroll
        for (int off = 32; off; off >>= 1) cnt = max(cnt, __shfl_xor(cnt, off, 64));
        int n4 = (cnt + 3) >> 2;
        n44[it] = min(n4, n4cap);
        bv4[it] = bias[col];
    }

    for (int r = t; r < IN_F; r += MAIN_THREADS) {
        unsigned u0 = x_bits(x[(b0 + 0) * IN_F + r]);
        unsigned u1 = x_bits(x[(b0 + 1) * IN_F + r]);
        unsigned u2 = x_bits(x[(b0 + 2) * IN_F + r]);
        unsigned u3 = x_bits(x[(b0 + 3) * IN_F + r]);
        unsigned u4 = x_bits(x[(b0 + 4) * IN_F + r]);
        unsigned u5 = x_bits(x[(b0 + 5) * IN_F + r]);
        unsigned u6 = x_bits(x[(b0 + 6) * IN_F + r]);
        unsigned u7 = x_bits(x[(b0 + 7) * IN_F + r]);
        uint4 d;
        d.x = (u1 << 16) | u0;
        d.y = (u3 << 16) | u2;
        d.z = (u5 << 16) | u4;
        d.w = (u7 << 16) | u6;
        xl[r] = d;
    }
    __syncthreads();

    const char* xbase = (const char*)xl;

#pragma unroll 1
    for (int it = 0; it < GROUPS_PER_WAVE; ++it) {
        int g = half * 64 + wave * GROUPS_PER_WAVE + it;
        int col = (g << 6) + lane;
        int n4 = n44[it];
        const uint4* ep = (const uint4*)(ell + (size_t)g * (L * 64));
        float bv = bv4[it];
#if USE_DOT2
        float a0 = 0.f, a1 = 0.f, a2 = 0.f, a3 = 0.f;
        float a4 = 0.f, a5 = 0.f, a6 = 0.f, a7 = 0.f;
        half2v p0 = half2v{}, p1 = half2v{}, p2 = half2v{}, p3 = half2v{};
        if (n4 > 0) {
            uint4 qA = ep[lane];
            uint4 xA0, xA1, xA2, xA3;
            LD4A(qA);
            uint4 qB;
            uint4 xB0, xB1, xB2, xB3;
            if (n4 > 1) {
                qB = ep[64 + lane];
                LD4B(qB);
            }
            int s4 = 2;
            int parity = 0;
#pragma unroll 1
            for (; s4 + 1 < n4; s4 += 2) {
                uint4 qC = ep[s4 * 64 + lane];          // global prefetch (quad s4)
                uint4 qD = ep[(s4 + 1) * 64 + lane];    // global prefetch (quad s4+1)
                PKQ(qA, xA0, xA1, xA2, xA3);            // consume quad s4-2
                qA = qC;
                LD4A(qA);                               // LDS refill for quad s4
                PKQ(qB, xB0, xB1, xB2, xB3);            // consume quad s4-1
                qB = qD;
                LD4B(qB);                               // LDS refill for quad s4+1
                if ((parity ^= 1) == 0) FOLD8();        // f32 fold every 16 entries
            }
            if (s4 < n4) {                              // one un-loaded quad remains
                uint4 qC = ep[s4 * 64 + lane];
                PKQ(qA, xA0, xA1, xA2, xA3);
                qA = qC;
                LD4A(qA);
                PKQ(qB, xB0, xB1, xB2, xB3);
                PKQ(qA, xA0, xA1, xA2, xA3);
            } else {
                PKQ(qA, xA0, xA1, xA2, xA3);
                if (n4 > 1) PKQ(qB, xB0, xB1, xB2, xB3);
            }
            FOLD8();
        }
        out[(size_t)(b0 + 0) * OUT_F + col] = a0 + bv;
        out[(size_t)(b0 + 1) * OUT_F + col] = a1 + bv;
        out[(size_t)(b0 + 2) * OUT_F + col] = a2 + bv;
        out[(size_t)(b0 + 3) * OUT_F + col] = a3 + bv;
        out[(size_t)(b0 + 4) * OUT_F + col] = a4 + bv;
        out[(size_t)(b0 + 5) * OUT_F + col] = a5 + bv;
        out[(size_t)(b0 + 6) * OUT_F + col] = a6 + bv;
        out[(size_t)(b0 + 7) * OUT_F + col] = a7 + bv;
#else
        f32x2 a01 = {0.f, 0.f}, a23 = {0.f, 0.f}, a45 = {0.f, 0.f}, a67 = {0.f, 0.f};
        if (n4 > 0) {
            uint4 q = ep[lane];
#pragma unroll 1
            for (int s4 = 1; s4 < n4; ++s4) {
                uint4 qn = ep[s4 * 64 + lane];
                process_entry8(q.x, xbase, a01, a23, a45, a67);
                process_entry8(q.y, xbase, a01, a23, a45, a67);
                process_entry8(q.z, xbase, a01, a23, a45, a67);
                process_entry8(q.w, xbase, a01, a23, a45, a67);
                q = qn;
            }
            process_entry8(q.x, xbase, a01, a23, a45, a67);
            process_entry8(q.y, xbase, a01, a23, a45, a67);
            process_entry8(q.z, xbase, a01, a23, a45, a67);
            process_entry8(q.w, xbase, a01, a23, a45, a67);
        }
        out[(size_t)(b0 + 0) * OUT_F + col] = a01.x + bv;
        out[(size_t)(b0 + 1) * OUT_F + col] = a01.y + bv;
        out[(size_t)(b0 + 2) * OUT_F + col] = a23.x + bv;
        out[(size_t)(b0 + 3) * OUT_F + col] = a23.y + bv;
        out[(size_t)(b0 + 4) * OUT_F + col] = a45.x + bv;
        out[(size_t)(b0 + 5) * OUT_F + col] = a45.y + bv;
        out[(size_t)(b0 + 6) * OUT_F + col] = a67.x + bv;
        out[(size_t)(b0 + 7) * OUT_F + col] = a67.y + bv;
#endif
    }
}

extern "C" void kernel_launch(void* const* d_in, const int* in_sizes, int n_in,
                              void* d_out, int out_size, void* d_ws, size_t ws_size,
                              hipStream_t stream) {
    const float* x      = (const float*)d_in[0];
    const float* values = (const float*)d_in[1];
    const float* bias   = (const float*)d_in[2];
    const int* rows = (const int*)d_in[3];
    const int* cols = (const int*)d_in[4];
    float* out = (float*)d_out;
    int nnz = in_sizes[1];

    int* bcnt   = (int*)d_ws;                    // 1024 dwords
    int* counts = bcnt + NBUCKET;                // 8192 dwords
    unsigned* ell = (unsigned*)(counts + 8192);  // 128 * 64 * L dwords

    // L = slots per column, multiple of 4, clamped to workspace capacity.
    long long cap_slots = ((long long)(ws_size / 4) - (NBUCKET + 8192)) / 8192;
    int L = (int)(cap_slots & ~3LL);
    if (L > L_PREF) L = L_PREF;
    if (L < 4) L = 4;

    static int attr_set = -1;                    // host-side only; no device effect
    if (attr_set < 0) {
        hipFuncSetAttribute((const void*)spmm_kernel,
                            hipFuncAttributeMaxDynamicSharedMemorySize, XTILE_BYTES);
        attr_set = 1;
    }

    hipMemsetAsync(bcnt, 0, NBUCKET * 4, stream);   // only bucket counters need zeroing
    int nb1 = (nnz + P1_CHUNK - 1) / P1_CHUNK;
    bin_kernel<<<nb1, P1_THREADS, 0, stream>>>(rows, cols, values, bcnt, ell, nnz, L);
    build_kernel<<<128, P2_THREADS, 0, stream>>>(bcnt, ell, counts, L);
    spmm_kernel<<<NBT * 2, MAIN_THREADS, XTILE_BYTES, stream>>>(x, bias, counts, ell, out, L);
}